// Round 14
// baseline (213.842 us; speedup 1.0000x reference)
//
#include <hip/hip_runtime.h>
#include <hip/hip_bf16.h>

#define N_NODES 100000
#define R_REL 4
#define E_EDGES 160000
#define D 128
#define NEG_SLOPE 0.2f
#define CAP 32     // max edges per dst (all relations); Poisson(6.4): P(>32)*100K ~ 1e-10
#define NB_DST 16  // dsts per k_aggproj block (100000/16 = 6250 blocks exactly)

typedef unsigned short u16x8 __attribute__((ext_vector_type(8)));
typedef unsigned short u16x4 __attribute__((ext_vector_type(4)));
typedef __bf16 bf16x8v __attribute__((ext_vector_type(8)));
typedef float f32x4 __attribute__((ext_vector_type(4)));

__device__ inline unsigned short f2bf(float f) {
    unsigned u = __float_as_uint(f);
    return (unsigned short)((u + 0x7FFFu + ((u >> 16) & 1u)) >> 16);
}
__device__ inline float bf2f(unsigned short h) {
    return __uint_as_float(((unsigned)h) << 16);
}

// fused setup: block 0 = prep (wl/wr/btot), blocks 1-32 = W transpose+cast,
// blocks 33..228 = zero cnt.
__global__ __launch_bounds__(512) void k_prep2(const float* __restrict__ Wsrc,
        const float* __restrict__ Wdst, const float* __restrict__ al,
        const float* __restrict__ ar, const float* __restrict__ gb,
        const float* __restrict__ hb, float* __restrict__ wl,
        float* __restrict__ wr, float* __restrict__ btot,
        unsigned short* __restrict__ Wt, unsigned* __restrict__ cnt) {
    int b = blockIdx.x, t = threadIdx.x;
    if (b == 0) {
        int r = t >> 7, d = t & 127;
        const float* as = al + r * D;
        const float* ad = ar + r * D;
        const float* rs = Wsrc + (r * D + d) * D;
        const float* rd = Wdst + (r * D + d) * D;
        float s0 = 0.f, s1 = 0.f;
        for (int e = 0; e < D; e++) { s0 += rs[e] * as[e]; s1 += rd[e] * ad[e]; }
        wl[r * D + d] = s0; wr[r * D + d] = s1;
        if (t < D) {
            float bb = hb[t];
            for (int r2 = 0; r2 < R_REL; r2++) bb += gb[r2 * D + t];
            btot[t] = bb;
        }
    } else if (b <= 32) {
        int base = (b - 1) * 2048 + t;
        #pragma unroll
        for (int i = 0; i < 4; i++) {
            int idx = base + i * 512;
            int r = idx >> 14; int rem = idx & 16383; int e = rem >> 7; int k = rem & 127;
            Wt[idx] = f2bf(Wsrc[(r * D + k) * D + e]);
        }
    } else {
        int i = (b - 33) * 512 + t;
        if (i < N_NODES) cnt[i] = 0u;
    }
}

// fused: coalesced read of x (wave covers 2 rows), emits xb (bf16 cast),
// el[r,n] = x[n]·wl[r], er[r,n] = x[n]·wr[r] via shuffle reduce
__global__ __launch_bounds__(256) void k_scores_cast(const float* __restrict__ x,
        const float* __restrict__ wl, const float* __restrict__ wr,
        unsigned short* __restrict__ xb, float* __restrict__ el, float* __restrict__ er) {
    __shared__ float swl[R_REL * D], swr[R_REL * D];
    int t = threadIdx.x;
    for (int i = t; i < R_REL * D; i += 256) { swl[i] = wl[i]; swr[i] = wr[i]; }
    __syncthreads();
    int wv = t >> 6, lane = t & 63;
    int half = lane >> 5, q = lane & 31;           // q: float4 index within row
    long n = (long)blockIdx.x * 8 + wv * 2 + half; // N divisible by 8 -> no tail
    float4 v = ((const float4*)(x + n * D))[q];
    u16x4 ov;
    ov[0] = f2bf(v.x); ov[1] = f2bf(v.y); ov[2] = f2bf(v.z); ov[3] = f2bf(v.w);
    *(u16x4*)(xb + n * D + q * 4) = ov;
    float accl[R_REL], accr[R_REL];
    #pragma unroll
    for (int r = 0; r < R_REL; r++) {
        float4 w = ((const float4*)(swl + r * D))[q];
        accl[r] = v.x * w.x + v.y * w.y + v.z * w.z + v.w * w.w;
        float4 u = ((const float4*)(swr + r * D))[q];
        accr[r] = v.x * u.x + v.y * u.y + v.z * u.z + v.w * u.w;
    }
    #pragma unroll
    for (int r = 0; r < R_REL; r++) {
        #pragma unroll
        for (int d = 16; d >= 1; d >>= 1) {
            accl[r] += __shfl_xor(accl[r], d);
            accr[r] += __shfl_xor(accr[r], d);
        }
    }
    if (q == 0) {
        #pragma unroll
        for (int r = 0; r < R_REL; r++) {
            el[r * N_NODES + n] = accl[r];
            er[r * N_NODES + n] = accr[r];
        }
    }
}

// per-edge pass (r9/r10-proven): gathers -> exp -> atomic -> bucket write
__global__ void k_scatter(const int* __restrict__ esrc, const int* __restrict__ edst,
                          const float* __restrict__ el, const float* __restrict__ er,
                          unsigned* __restrict__ cnt, int2* __restrict__ eb) {
    int e = blockIdx.x * 256 + threadIdx.x;
    if (e >= E_EDGES) return;
    int r = blockIdx.y;
    int t = r * E_EDGES + e;
    int src = esrc[t], dst = edst[t];
    float lg = el[r * N_NODES + src] + er[r * N_NODES + dst];
    lg = lg > 0.f ? lg : NEG_SLOPE * lg;
    float p = __expf(lg);
    unsigned pos = atomicAdd(cnt + dst, 1u);
    if (pos < CAP) eb[dst * CAP + pos] = make_int2(r * N_NODES + src, __float_as_int(p));
}

// LINEARITY-RESTRUCTURED aggregation+projection (replaces hs GEMM + hs gather):
// sum_e alpha*(xb[src]@W_r) == (sum_e alpha*xb[src]) @ W_r.
// Phase A: per-dst in-wave softmax (r9 2-dst scheme) + per-relation z
// aggregation from L3-resident xb; z -> LDS bf16.
// Phase B: out[16 dsts] = relu(sum_r Z_r @ W_r + btot) via the validated
// gemm_body MFMA fragment pattern (W^T fragments from global, 64 KB L2-hot).
__global__ __launch_bounds__(256) void k_aggproj(
        const int2* __restrict__ eb, const unsigned* __restrict__ cnt,
        const unsigned short* __restrict__ xb, const unsigned short* __restrict__ Wt,
        const float* __restrict__ btot, float* __restrict__ out) {
    __shared__ unsigned short Z[R_REL][NB_DST][D + 8];
    int tid = threadIdx.x;
    int wv = tid >> 6, lane = tid & 63;
    int half = lane >> 5, l32 = lane & 31;
    int slot2 = l32 >> 4, c16 = lane & 15;
    int dbase = blockIdx.x * NB_DST;
    // ---- Phase A: each wave aggregates 4 dsts via 2 passes of the 2-dst scheme
    for (int ps = 0; ps < 2; ps++) {
        int dloc = wv * 4 + ps * 2 + half;
        int dst = dbase + dloc;
        int2 m = eb[dst * CAP + l32];            // issued parallel with cnt load
        unsigned num = cnt[dst];
        if (num > CAP) num = CAP;
        bool live = (unsigned)l32 < num;
        int rowid = live ? m.x : 0;              // rowid = r*N + src
        float pv = live ? __int_as_float(m.y) : 0.f;
        int r = live ? (int)((unsigned)rowid / (unsigned)N_NODES) : 0;
        // per-relation denominators: width-32 butterflies, full EXEC
        float denom[R_REL];
        #pragma unroll
        for (int rr = 0; rr < R_REL; rr++) {
            float v = (r == rr) ? pv : 0.f;
            #pragma unroll
            for (int d = 1; d < 32; d <<= 1) v += __shfl_xor(v, d, 32);
            denom[rr] = v;
        }
        float alpha = live ? pv / denom[r] : 0.f;
        // gather xb rows; accumulate per-relation z (static indices only).
        // UNIFORM trip count; all shfl at full EXEC (r3/4 lesson).
        float accz[R_REL][8];
        #pragma unroll
        for (int rr = 0; rr < R_REL; rr++)
            #pragma unroll
            for (int j = 0; j < 8; j++) accz[rr][j] = 0.f;
        unsigned numo = __shfl_xor(num, 32);
        unsigned numMax = num > numo ? num : numo;
        unsigned iters = (numMax + 1) >> 1;
        for (unsigned i = 0; i < iters; i++) {
            unsigned q = slot2 + i * 2;          // q <= 31
            int srcl = half * 32 + (int)q;
            int rid = __shfl(rowid, srcl);
            float al = __shfl(alpha, srcl);
            if (q < num) {
                unsigned rr_e = (unsigned)rid / (unsigned)N_NODES;
                int sidx = rid - (int)(rr_e * (unsigned)N_NODES);
                u16x8 v = *(const u16x8*)(xb + (long)sidx * D + c16 * 8);
                #pragma unroll
                for (int rr = 0; rr < R_REL; rr++) {
                    float alc = (rr_e == (unsigned)rr) ? al : 0.f;
                    #pragma unroll
                    for (int j = 0; j < 8; j++) accz[rr][j] += alc * bf2f(v[j]);
                }
            }
        }
        #pragma unroll
        for (int rr = 0; rr < R_REL; rr++)
            #pragma unroll
            for (int j = 0; j < 8; j++) accz[rr][j] += __shfl_xor(accz[rr][j], 16);
        if (slot2 == 0) {                        // lanes c16 of each half
            #pragma unroll
            for (int rr = 0; rr < R_REL; rr++) {
                u16x8 zv;
                #pragma unroll
                for (int j = 0; j < 8; j++) zv[j] = f2bf(accz[rr][j]);
                *(u16x8*)(&Z[rr][dloc][c16 * 8]) = zv;
            }
        }
    }
    __syncthreads();
    // ---- Phase B: 16x128 output tile; wave wv owns feature-tiles et = wv*2, wv*2+1
    int row16 = lane & 15, kgrp = lane >> 4;
    f32x4 acc0, acc1;
    acc0[0] = 0.f; acc0[1] = 0.f; acc0[2] = 0.f; acc0[3] = 0.f;
    acc1 = acc0;
    #pragma unroll
    for (int rr = 0; rr < R_REL; rr++) {
        const unsigned short* Wr = Wt + rr * D * D;
        #pragma unroll
        for (int kf = 0; kf < 4; kf++) {
            bf16x8v az = *(const bf16x8v*)(&Z[rr][row16][kf * 32 + kgrp * 8]);
            bf16x8v av0 = *(const bf16x8v*)(Wr + ((wv * 2) * 16 + row16) * D + kf * 32 + kgrp * 8);
            bf16x8v av1 = *(const bf16x8v*)(Wr + ((wv * 2 + 1) * 16 + row16) * D + kf * 32 + kgrp * 8);
            acc0 = __builtin_amdgcn_mfma_f32_16x16x32_bf16(av0, az, acc0, 0, 0, 0);
            acc1 = __builtin_amdgcn_mfma_f32_16x16x32_bf16(av1, az, acc1, 0, 0, 0);
        }
    }
    // C layout (validated in gemm_body): lane row16 = dst col, feature = et*16+kgrp*4+j
    float* orow = out + (long)(dbase + row16) * D;
    int c0 = wv * 32 + kgrp * 4;          // et0*16 + kgrp*4
    const float4 b0 = *(const float4*)(btot + c0);
    const float4 b1 = *(const float4*)(btot + c0 + 16);
    float4 o0, o1;
    o0.x = acc0[0] + b0.x; o0.y = acc0[1] + b0.y; o0.z = acc0[2] + b0.z; o0.w = acc0[3] + b0.w;
    o1.x = acc1[0] + b1.x; o1.y = acc1[1] + b1.y; o1.z = acc1[2] + b1.z; o1.w = acc1[3] + b1.w;
    o0.x = o0.x > 0.f ? o0.x : 0.f; o0.y = o0.y > 0.f ? o0.y : 0.f;
    o0.z = o0.z > 0.f ? o0.z : 0.f; o0.w = o0.w > 0.f ? o0.w : 0.f;
    o1.x = o1.x > 0.f ? o1.x : 0.f; o1.y = o1.y > 0.f ? o1.y : 0.f;
    o1.z = o1.z > 0.f ? o1.z : 0.f; o1.w = o1.w > 0.f ? o1.w : 0.f;
    *(float4*)(orow + c0) = o0;
    *(float4*)(orow + c0 + 16) = o1;
}

extern "C" void kernel_launch(void* const* d_in, const int* in_sizes, int n_in,
                              void* d_out, int out_size, void* d_ws, size_t ws_size,
                              hipStream_t stream) {
    const float* x    = (const float*)d_in[0];
    const int*   esrc = (const int*)d_in[1];
    const int*   edst = (const int*)d_in[2];
    const float* Wsrc = (const float*)d_in[3];
    const float* Wdst = (const float*)d_in[4];
    const float* al   = (const float*)d_in[5];
    const float* ar   = (const float*)d_in[6];
    const float* gb   = (const float*)d_in[7];
    const float* hb   = (const float*)d_in[8];
    float* out = (float*)d_out;

    char* ws = (char*)d_ws;
    size_t o = 0;
    auto alloc = [&](size_t bytes) -> char* {
        char* r = ws + o; o += (bytes + 255) & ~(size_t)255; return r;
    };
    unsigned short* xb  = (unsigned short*)alloc((size_t)N_NODES * D * 2);   // 25.6 MB
    unsigned short* Wt  = (unsigned short*)alloc((size_t)R_REL * D * D * 2);
    float* el   = (float*)alloc((size_t)R_REL * N_NODES * 4);
    float* er   = (float*)alloc((size_t)R_REL * N_NODES * 4);
    float* wl   = (float*)alloc(R_REL * D * 4);
    float* wr   = (float*)alloc(R_REL * D * 4);
    float* btot = (float*)alloc(D * 4);
    unsigned* cnt = (unsigned*)alloc((size_t)N_NODES * 4);
    int2* eb = (int2*)alloc((size_t)N_NODES * CAP * 8);          // 25.6 MB
    // total ~55 MB (hs deleted entirely)

    int zblocks = (N_NODES + 511) / 512;                 // 196
    k_prep2<<<dim3(33 + zblocks), dim3(512), 0, stream>>>(Wsrc, Wdst, al, ar, gb, hb,
                                                          wl, wr, btot, Wt, cnt);
    k_scores_cast<<<dim3(N_NODES / 8), dim3(256), 0, stream>>>(x, wl, wr, xb, el, er);
    k_scatter<<<dim3(E_EDGES / 256, R_REL), dim3(256), 0, stream>>>(esrc, edst, el, er, cnt, eb);
    k_aggproj<<<dim3(N_NODES / NB_DST), dim3(256), 0, stream>>>(eb, cnt, xb, Wt, btot, out);
}